// Round 5
// baseline (144.784 us; speedup 1.0000x reference)
//
#include <hip/hip_runtime.h>
#include <hip/hip_bf16.h>

#define NPTS 8192
#define NB 4
#define NC 13
#define KTOP 16
#define RPB 32        // rows per block: 4 waves x 8 rows
#define CAP 128       // per-row candidate capacity
#define CAPP 129      // padded stride (bank-conflict)
#define NPAIR (NPTS/2)

typedef unsigned long long ull;
typedef float __attribute__((ext_vector_type(2))) f32x2;

__device__ __forceinline__ float rfl(float x) {
    return __uint_as_float(__builtin_amdgcn_readfirstlane(__float_as_uint(x)));
}
__device__ __forceinline__ unsigned sortable(float s) {
    unsigned u = __float_as_uint(s);
    return u ^ ((u & 0x80000000u) ? 0xFFFFFFFFu : 0x80000000u);
}
// packed 2xf32 fma: d = a*b + c   (full-rate on CDNA2+)
__device__ __forceinline__ f32x2 pk_fma(f32x2 a, f32x2 b, f32x2 c) {
    f32x2 d;
    asm("v_pk_fma_f32 %0, %1, %2, %3" : "=v"(d) : "v"(a), "v"(b), "v"(c));
    return d;
}
__device__ __forceinline__ float max3f(float a, float b, float c) {
    float d;
    asm("v_max3_f32 %0, %1, %2, %3" : "=v"(d) : "v"(a), "v"(b), "v"(c));
    return d;
}

// ---------------- kernel A: prep (pairs + rgb transpose + softmax) ----------------
__global__ __launch_bounds__(256) void prep_kernel(
    const float* __restrict__ logits, const float* __restrict__ xyz,
    const float* __restrict__ rgb,
    float4* __restrict__ pairA, float4* __restrict__ pairB,
    float4* __restrict__ rgbt, float4* __restrict__ probst)
{
    int gid = blockIdx.x * 256 + threadIdx.x;      // 0 .. B*N-1
    int b = gid >> 13, n = gid & (NPTS - 1);

    const float* xb = xyz + b * 3 * NPTS;
    float x0 = xb[n], x1 = xb[NPTS + n], x2 = xb[2 * NPTS + n];
    float w = -0.5f * (x0 * x0 + x1 * x1 + x2 * x2);

    // pair layout: A = {x_even, x_odd, y_even, y_odd}, B = {z_e, z_o, w_e, w_o}
    float nx = __shfl_down(x0, 1), ny = __shfl_down(x1, 1);
    float nz = __shfl_down(x2, 1), nw = __shfl_down(w, 1);
    if (!(n & 1)) {
        pairA[gid >> 1] = make_float4(x0, nx, x1, ny);
        pairB[gid >> 1] = make_float4(x2, nz, w, nw);
    }

    const float* rb = rgb + b * 3 * NPTS;
    rgbt[gid] = make_float4(rb[n], rb[NPTS + n], rb[2 * NPTS + n], 0.f);

    const float* lb = logits + b * NC * NPTS;
    float l[NC];
    float mx = -1e30f;
    #pragma unroll
    for (int c = 0; c < NC; ++c) { l[c] = lb[c * NPTS + n]; mx = fmaxf(mx, l[c]); }
    float sum = 0.f;
    #pragma unroll
    for (int c = 0; c < NC; ++c) { l[c] = __expf(l[c] - mx); sum += l[c]; }
    float inv = 1.0f / sum;
    #pragma unroll
    for (int c = 0; c < NC; ++c) l[c] *= inv;

    float4* dst = probst + (size_t)gid * 4;
    dst[0] = make_float4(l[0], l[1], l[2], l[3]);
    dst[1] = make_float4(l[4], l[5], l[6], l[7]);
    dst[2] = make_float4(l[8], l[9], l[10], l[11]);
    dst[3] = make_float4(l[12], 0.f, 0.f, 0.f);   // pads contribute |0-0| = 0
}

// ---------------- kernel B: exact top-16 + loss ----------------
// 256 threads = 4 waves; wave owns 8 rows (queries in broadcast VGPR pairs),
// lanes pair-parallel. grid = NB*NPTS/RPB = 1024 blocks.
__global__ __launch_bounds__(256, 4) void topk_loss_kernel(
    const float4* __restrict__ pairA, const float4* __restrict__ pairB,
    const float4* __restrict__ rgbt, const float4* __restrict__ probst,
    float* __restrict__ partials)
{
    __shared__ unsigned int s_cnt[RPB];
    __shared__ ull s_list[RPB][CAPP];    // 33 KB, padded stride
    __shared__ float s_wred[4];

    const int tid = threadIdx.x;
    const int w = tid >> 6, lane = tid & 63;
    const int b = blockIdx.x >> 8;                // 256 blocks per batch
    const int nbase = (blockIdx.x & 255) * RPB;
    const int rw = w * 8;
    const int b8 = b * NPTS;
    const float4* pA = pairA + b * NPAIR;
    const float4* pB = pairB + b * NPAIR;

    if (tid < RPB) s_cnt[tid] = 0;
    __syncthreads();

    // queries: row n -> pair n>>1, half n&1 (= r&1 since nbase, rw even)
    f32x2 qx[8], qy[8], qz[8];
    #pragma unroll
    for (int r = 0; r < 8; ++r) {
        int n = nbase + rw + r;
        float4 A = pA[n >> 1];
        float4 B = pB[n >> 1];
        float sx = rfl((r & 1) ? A.y : A.x);
        float sy = rfl((r & 1) ? A.w : A.z);
        float sz = rfl((r & 1) ? B.y : B.x);
        qx[r] = (f32x2){sx, sx}; qy[r] = (f32x2){sy, sy}; qz[r] = (f32x2){sz, sz};
    }

    // ---- phase 1: per-(lane,row) running max; 2 points per packed step ----
    float bk[8];
    #pragma unroll
    for (int r = 0; r < 8; ++r) bk[r] = -3.0e38f;

    #pragma unroll 2
    for (int t = 0; t < NPAIR / 64; ++t) {        // 64 tiles x 64 pairs
        float4 A = pA[t * 64 + lane];
        float4 B = pB[t * 64 + lane];
        f32x2 xs = {A.x, A.y}, ys = {A.z, A.w}, zs = {B.x, B.y}, ws = {B.z, B.w};
        #pragma unroll
        for (int r = 0; r < 8; ++r) {
            f32x2 s = pk_fma(qx[r], xs, pk_fma(qy[r], ys, pk_fma(qz[r], zs, ws)));
            bk[r] = max3f(bk[r], s.x, s.y);
        }
    }

    // ---- threshold: min over 8 buckets (8 lanes each) of bucket top-2 ----
    // 16 distinct point-scores >= thr  =>  thr <= s_(16): exact superset.
    float thr[8];
    #pragma unroll
    for (int r = 0; r < 8; ++r) {
        float m1 = bk[r], m2 = -3.0e38f;
        #pragma unroll
        for (int mk = 1; mk < 8; mk <<= 1) {
            float p1 = __shfl_xor(m1, mk), p2 = __shfl_xor(m2, mk);
            float lo = fminf(m1, p1);
            m1 = fmaxf(m1, p1);
            m2 = fmaxf(lo, fmaxf(m2, p2));
        }
        #pragma unroll
        for (int mk = 8; mk < 64; mk <<= 1)
            m2 = fminf(m2, __shfl_xor(m2, mk));
        thr[r] = rfl(m2);
    }

    // ---- phase 2: rescan, append candidates with s >= thr ----
    #pragma unroll 2
    for (int t = 0; t < NPAIR / 64; ++t) {
        float4 A = pA[t * 64 + lane];
        float4 B = pB[t * 64 + lane];
        f32x2 xs = {A.x, A.y}, ys = {A.z, A.w}, zs = {B.x, B.y}, ws = {B.z, B.w};
        int m0 = (t * 64 + lane) * 2;
        #pragma unroll
        for (int r = 0; r < 8; ++r) {
            f32x2 s = pk_fma(qx[r], xs, pk_fma(qy[r], ys, pk_fma(qz[r], zs, ws)));
            if (fmaxf(s.x, s.y) >= thr[r]) {       // rare (p~0.4/row-tile)
                int row = rw + r;
                if (s.x >= thr[r]) {
                    unsigned slot = atomicAdd(&s_cnt[row], 1u);
                    if (slot < CAP)
                        s_list[row][slot] = ((ull)sortable(s.x) << 13) | (ull)(8191 - m0);
                }
                if (s.y >= thr[r]) {
                    unsigned slot = atomicAdd(&s_cnt[row], 1u);
                    if (slot < CAP)
                        s_list[row][slot] = ((ull)sortable(s.y) << 13) | (ull)(8191 - m0 - 1);
                }
            }
        }
    }
    __syncthreads();

    // ---- phase 3: rank-count selection + loss terms (8 lanes per row) ----
    const int row = tid >> 3;            // 0..31
    const int i0 = tid & 7;
    const int nrow = nbase + row;
    const int cnt = min((int)s_cnt[row], CAP);    // >= 16 guaranteed

    float4 crgb = rgbt[b8 + nrow];
    const float4* cp = probst + (size_t)(b8 + nrow) * 4;
    float4 cp0 = cp[0], cp1 = cp[1], cp2 = cp[2], cp3 = cp[3];

    float acc = 0.f;
    for (int j = i0; j < cnt; j += 8) {
        ull kj = s_list[row][j];
        int rank = 0;
        for (int j2 = 0; j2 < cnt; ++j2) rank += (s_list[row][j2] > kj);
        if (rank < KTOP) {                        // exact top-16 member
            int m = 8191 - (int)(kj & 0x1FFFull);
            float4 nr = rgbt[b8 + m];
            const float4* np4 = probst + (size_t)(b8 + m) * 4;
            float4 q0 = np4[0], q1 = np4[1], q2 = np4[2], q3 = np4[3];
            float dx = crgb.x - nr.x, dy = crgb.y - nr.y, dz = crgb.z - nr.z;
            float rd = sqrtf(fmaf(dx, dx, fmaf(dy, dy, dz * dz)));
            float pd = fabsf(cp0.x-q0.x)+fabsf(cp0.y-q0.y)+fabsf(cp0.z-q0.z)+fabsf(cp0.w-q0.w)
                     + fabsf(cp1.x-q1.x)+fabsf(cp1.y-q1.y)+fabsf(cp1.z-q1.z)+fabsf(cp1.w-q1.w)
                     + fabsf(cp2.x-q2.x)+fabsf(cp2.y-q2.y)+fabsf(cp2.z-q2.z)+fabsf(cp2.w-q2.w)
                     + fabsf(cp3.x-q3.x)+fabsf(cp3.y-q3.y)+fabsf(cp3.z-q3.z)+fabsf(cp3.w-q3.w);
            acc = fmaf(__expf(-10.0f * rd), pd, acc);
        }
    }

    // fixed-tree deterministic reduce: wave -> block -> partials
    #pragma unroll
    for (int off = 32; off > 0; off >>= 1) acc += __shfl_down(acc, off);
    if (lane == 0) s_wred[w] = acc;
    __syncthreads();
    if (tid == 0) partials[blockIdx.x] = s_wred[0] + s_wred[1] + s_wred[2] + s_wred[3];
}

// ---------------- kernel C: final reduce (1024 partials) ----------------
__global__ __launch_bounds__(256) void reduce_kernel(const float* __restrict__ partials,
                                                     float* __restrict__ out) {
    __shared__ float s[256];
    int tid = threadIdx.x;
    s[tid] = partials[tid] + partials[tid + 256] + partials[tid + 512] + partials[tid + 768];
    __syncthreads();
    if (tid < 128) s[tid] += s[tid + 128];
    __syncthreads();
    if (tid < 64) {
        float x = s[tid] + s[tid + 64];
        for (int off = 32; off > 0; off >>= 1) x += __shfl_down(x, off);
        if (tid == 0) out[0] = x * (1.0f / (float)(NB * NPTS * KTOP));
    }
}

extern "C" void kernel_launch(void* const* d_in, const int* in_sizes, int n_in,
                              void* d_out, int out_size, void* d_ws, size_t ws_size,
                              hipStream_t stream) {
    (void)in_sizes; (void)n_in; (void)out_size; (void)ws_size;
    const float* logits = (const float*)d_in[0];
    const float* xyz    = (const float*)d_in[1];
    const float* rgb    = (const float*)d_in[2];

    float4* pairA  = (float4*)d_ws;            // 16384 float4 (256 KB)
    float4* pairB  = pairA + NB * NPAIR;       // 16384 float4 (256 KB)
    float4* rgbt   = pairB + NB * NPAIR;       // 32768 float4 (512 KB)
    float4* probst = rgbt + NB * NPTS;         // 131072 float4 (2 MB)
    float*  partials = (float*)(probst + (size_t)NB * NPTS * 4);  // 1024 floats

    prep_kernel<<<NB * NPTS / 256, 256, 0, stream>>>(logits, xyz, rgb, pairA, pairB, rgbt, probst);
    topk_loss_kernel<<<NB * NPTS / RPB, 256, 0, stream>>>(pairA, pairB, rgbt, probst, partials);
    reduce_kernel<<<1, 256, 0, stream>>>(partials, (float*)d_out);
}

// Round 6
// 113.659 us; speedup vs baseline: 1.2738x; 1.2738x over previous
//
#include <hip/hip_runtime.h>
#include <hip/hip_bf16.h>

#define NPTS 8192
#define NB 4
#define NC 13
#define KTOP 16
#define RPB 16        // rows per block: 4 waves x 4 rows
#define CAP 128       // per-row candidate capacity
#define CAPP 129      // padded stride (bank-conflict fix)
#define NPAIR (NPTS/2)

typedef unsigned long long ull;
typedef float __attribute__((ext_vector_type(2))) f32x2;

__device__ __forceinline__ float rfl(float x) {
    return __uint_as_float(__builtin_amdgcn_readfirstlane(__float_as_uint(x)));
}
__device__ __forceinline__ unsigned sortable(float s) {
    unsigned u = __float_as_uint(s);
    return u ^ ((u & 0x80000000u) ? 0xFFFFFFFFu : 0x80000000u);
}
// packed fma via generic builtin -> ISel picks v_pk_fma_f32 (no asm fences)
__device__ __forceinline__ f32x2 pkfma(f32x2 a, f32x2 b, f32x2 c) {
    return __builtin_elementwise_fma(a, b, c);
}

// ---------------- kernel A: prep (interleaved pairs + rgb + softmax) ----------------
// pairs[2*i]   = {x_e, x_o, y_e, y_o}
// pairs[2*i+1] = {z_e, z_o, w_e, w_o}   (w = -0.5*||p||^2)
__global__ __launch_bounds__(256) void prep_kernel(
    const float* __restrict__ logits, const float* __restrict__ xyz,
    const float* __restrict__ rgb,
    float4* __restrict__ pairs, float4* __restrict__ rgbt,
    float4* __restrict__ probst)
{
    int gid = blockIdx.x * 256 + threadIdx.x;      // 0 .. B*N-1
    int b = gid >> 13, n = gid & (NPTS - 1);

    const float* xb = xyz + b * 3 * NPTS;
    float x0 = xb[n], x1 = xb[NPTS + n], x2 = xb[2 * NPTS + n];
    float w = -0.5f * (x0 * x0 + x1 * x1 + x2 * x2);

    float nx = __shfl_down(x0, 1), ny = __shfl_down(x1, 1);
    float nz = __shfl_down(x2, 1), nw = __shfl_down(w, 1);
    if (!(n & 1)) {                                // even lanes: lane+1 valid
        pairs[(gid >> 1) * 2]     = make_float4(x0, nx, x1, ny);
        pairs[(gid >> 1) * 2 + 1] = make_float4(x2, nz, w, nw);
    }

    const float* rb = rgb + b * 3 * NPTS;
    rgbt[gid] = make_float4(rb[n], rb[NPTS + n], rb[2 * NPTS + n], 0.f);

    const float* lb = logits + b * NC * NPTS;
    float l[NC];
    float mx = -1e30f;
    #pragma unroll
    for (int c = 0; c < NC; ++c) { l[c] = lb[c * NPTS + n]; mx = fmaxf(mx, l[c]); }
    float sum = 0.f;
    #pragma unroll
    for (int c = 0; c < NC; ++c) { l[c] = __expf(l[c] - mx); sum += l[c]; }
    float inv = 1.0f / sum;
    #pragma unroll
    for (int c = 0; c < NC; ++c) l[c] *= inv;

    float4* dst = probst + (size_t)gid * 4;
    dst[0] = make_float4(l[0], l[1], l[2], l[3]);
    dst[1] = make_float4(l[4], l[5], l[6], l[7]);
    dst[2] = make_float4(l[8], l[9], l[10], l[11]);
    dst[3] = make_float4(l[12], 0.f, 0.f, 0.f);   // pads contribute |0-0| = 0
}

// ---------------- kernel B: exact top-16 + loss ----------------
// 256 threads = 4 waves; wave owns 4 rows, lanes pair-parallel.
// grid = NB * NPTS / RPB = 2048 blocks -> 8 blocks/CU.
__global__ __launch_bounds__(256, 8) void topk_loss_kernel(
    const float4* __restrict__ pairs, const float4* __restrict__ rgbt,
    const float4* __restrict__ probst, float* __restrict__ partials)
{
    __shared__ unsigned int s_cnt[RPB];
    __shared__ ull s_list[RPB][CAPP];    // 16.5 KB padded
    __shared__ float s_wred[4];

    const int tid = threadIdx.x;
    const int w = tid >> 6, lane = tid & 63;
    const int b = blockIdx.x >> 9;                // 512 blocks per batch
    const int nbase = (blockIdx.x & 511) * RPB;
    const int rw = w * 4;
    const int b8 = b * NPTS;
    const float4* pp = pairs + (size_t)b * NPAIR * 2;

    if (tid < RPB) s_cnt[tid] = 0;
    __syncthreads();

    // wave-uniform queries (SGPR via readfirstlane), broadcast into f32x2
    f32x2 qx[4], qy[4], qz[4];
    #pragma unroll
    for (int r = 0; r < 4; ++r) {
        int n = nbase + rw + r;
        float4 A = pp[(n >> 1) * 2];
        float4 B = pp[(n >> 1) * 2 + 1];
        float sx = rfl((r & 1) ? A.y : A.x);
        float sy = rfl((r & 1) ? A.w : A.z);
        float sz = rfl((r & 1) ? B.y : B.x);
        qx[r] = (f32x2){sx, sx}; qy[r] = (f32x2){sy, sy}; qz[r] = (f32x2){sz, sz};
    }

    // ---- phase 1: per-(lane,row) running max; 2 points per packed step ----
    float bk[4];
    #pragma unroll
    for (int r = 0; r < 4; ++r) bk[r] = -3.0e38f;

    #pragma unroll 2
    for (int t = 0; t < NPAIR / 64; ++t) {        // 64 tiles x 64 pairs
        float4 A = pp[(t * 64 + lane) * 2];
        float4 B = pp[(t * 64 + lane) * 2 + 1];
        f32x2 xs = {A.x, A.y}, ys = {A.z, A.w}, zs = {B.x, B.y}, ws = {B.z, B.w};
        #pragma unroll
        for (int r = 0; r < 4; ++r) {
            f32x2 s = pkfma(qx[r], xs, pkfma(qy[r], ys, pkfma(qz[r], zs, ws)));
            bk[r] = fmaxf(bk[r], fmaxf(s.x, s.y));   // -> v_max3_f32
        }
    }

    // ---- threshold: min over 8 buckets (8 lanes each) of bucket top-2 ----
    // 16 distinct point-scores >= thr  =>  thr <= s_(16): exact superset.
    float thr[4];
    #pragma unroll
    for (int r = 0; r < 4; ++r) {
        float m1 = bk[r], m2 = -3.0e38f;
        #pragma unroll
        for (int mk = 1; mk < 8; mk <<= 1) {
            float p1 = __shfl_xor(m1, mk), p2 = __shfl_xor(m2, mk);
            float lo = fminf(m1, p1);
            m1 = fmaxf(m1, p1);
            m2 = fmaxf(lo, fmaxf(m2, p2));
        }
        #pragma unroll
        for (int mk = 8; mk < 64; mk <<= 1)
            m2 = fminf(m2, __shfl_xor(m2, mk));
        thr[r] = rfl(m2);
    }

    // ---- phase 2: rescan, append candidates with s >= thr ----
    #pragma unroll 2
    for (int t = 0; t < NPAIR / 64; ++t) {
        float4 A = pp[(t * 64 + lane) * 2];
        float4 B = pp[(t * 64 + lane) * 2 + 1];
        f32x2 xs = {A.x, A.y}, ys = {A.z, A.w}, zs = {B.x, B.y}, ws = {B.z, B.w};
        int m0 = (t * 64 + lane) * 2;
        #pragma unroll
        for (int r = 0; r < 4; ++r) {
            f32x2 s = pkfma(qx[r], xs, pkfma(qy[r], ys, pkfma(qz[r], zs, ws)));
            if (fmaxf(s.x, s.y) >= thr[r]) {       // rare path
                int row = rw + r;
                if (s.x >= thr[r]) {
                    unsigned slot = atomicAdd(&s_cnt[row], 1u);
                    if (slot < CAP)
                        s_list[row][slot] = ((ull)sortable(s.x) << 13) | (ull)(8191 - m0);
                }
                if (s.y >= thr[r]) {
                    unsigned slot = atomicAdd(&s_cnt[row], 1u);
                    if (slot < CAP)
                        s_list[row][slot] = ((ull)sortable(s.y) << 13) | (ull)(8191 - m0 - 1);
                }
            }
        }
    }
    __syncthreads();

    // ---- phase 3: rank-count selection + loss terms (16 lanes per row) ----
    const int row = tid >> 4;            // 0..15
    const int i0 = tid & 15;
    const int nrow = nbase + row;
    const int cnt = min((int)s_cnt[row], CAP);    // >= 16 guaranteed

    float4 crgb = rgbt[b8 + nrow];
    const float4* cp = probst + (size_t)(b8 + nrow) * 4;
    float4 cp0 = cp[0], cp1 = cp[1], cp2 = cp[2], cp3 = cp[3];

    float acc = 0.f;
    for (int j = i0; j < cnt; j += 16) {
        ull kj = s_list[row][j];
        int rank = 0;
        for (int j2 = 0; j2 < cnt; ++j2) rank += (s_list[row][j2] > kj);
        if (rank < KTOP) {                        // exact top-16 member
            int m = 8191 - (int)(kj & 0x1FFFull);
            float4 nr = rgbt[b8 + m];
            const float4* np4 = probst + (size_t)(b8 + m) * 4;
            float4 q0 = np4[0], q1 = np4[1], q2 = np4[2], q3 = np4[3];
            float dx = crgb.x - nr.x, dy = crgb.y - nr.y, dz = crgb.z - nr.z;
            float rd = sqrtf(fmaf(dx, dx, fmaf(dy, dy, dz * dz)));
            float pd = fabsf(cp0.x-q0.x)+fabsf(cp0.y-q0.y)+fabsf(cp0.z-q0.z)+fabsf(cp0.w-q0.w)
                     + fabsf(cp1.x-q1.x)+fabsf(cp1.y-q1.y)+fabsf(cp1.z-q1.z)+fabsf(cp1.w-q1.w)
                     + fabsf(cp2.x-q2.x)+fabsf(cp2.y-q2.y)+fabsf(cp2.z-q2.z)+fabsf(cp2.w-q2.w)
                     + fabsf(cp3.x-q3.x)+fabsf(cp3.y-q3.y)+fabsf(cp3.z-q3.z)+fabsf(cp3.w-q3.w);
            acc = fmaf(__expf(-10.0f * rd), pd, acc);
        }
    }

    // fixed-tree deterministic reduce: wave -> block -> partials
    #pragma unroll
    for (int off = 32; off > 0; off >>= 1) acc += __shfl_down(acc, off);
    if (lane == 0) s_wred[w] = acc;
    __syncthreads();
    if (tid == 0) partials[blockIdx.x] = s_wred[0] + s_wred[1] + s_wred[2] + s_wred[3];
}

// ---------------- kernel C: final reduce (2048 partials) ----------------
__global__ __launch_bounds__(256) void reduce_kernel(const float* __restrict__ partials,
                                                     float* __restrict__ out) {
    __shared__ float s[256];
    int tid = threadIdx.x;
    float v = 0.f;
    #pragma unroll
    for (int i = 0; i < 8; ++i) v += partials[tid + 256 * i];
    s[tid] = v;
    __syncthreads();
    if (tid < 128) s[tid] += s[tid + 128];
    __syncthreads();
    if (tid < 64) {
        float x = s[tid] + s[tid + 64];
        for (int off = 32; off > 0; off >>= 1) x += __shfl_down(x, off);
        if (tid == 0) out[0] = x * (1.0f / (float)(NB * NPTS * KTOP));
    }
}

extern "C" void kernel_launch(void* const* d_in, const int* in_sizes, int n_in,
                              void* d_out, int out_size, void* d_ws, size_t ws_size,
                              hipStream_t stream) {
    (void)in_sizes; (void)n_in; (void)out_size; (void)ws_size;
    const float* logits = (const float*)d_in[0];
    const float* xyz    = (const float*)d_in[1];
    const float* rgb    = (const float*)d_in[2];

    float4* pairs  = (float4*)d_ws;            // 32768 float4 (512 KB)
    float4* rgbt   = pairs + (size_t)NB * NPAIR * 2;   // 32768 float4 (512 KB)
    float4* probst = rgbt + NB * NPTS;         // 131072 float4 (2 MB)
    float*  partials = (float*)(probst + (size_t)NB * NPTS * 4);  // 2048 floats

    prep_kernel<<<NB * NPTS / 256, 256, 0, stream>>>(logits, xyz, rgb, pairs, rgbt, probst);
    topk_loss_kernel<<<NB * NPTS / RPB, 256, 0, stream>>>(pairs, rgbt, probst, partials);
    reduce_kernel<<<1, 256, 0, stream>>>(partials, (float*)d_out);
}